// Round 8
// baseline (529.305 us; speedup 1.0000x reference)
//
#include <hip/hip_runtime.h>

typedef unsigned short u16;
typedef unsigned short ushort8 __attribute__((ext_vector_type(8)));
typedef unsigned short us4 __attribute__((ext_vector_type(4)));
typedef __bf16 bf16x8 __attribute__((ext_vector_type(8)));
typedef float f32x4 __attribute__((ext_vector_type(4)));

#define DEV static __device__ __forceinline__

// ---------- helpers ----------
DEV u16 f2bf(float f) {   // round-to-nearest-even f32 -> bf16
    unsigned int u = __builtin_bit_cast(unsigned int, f);
    u += 0x7FFFu + ((u >> 16) & 1u);
    return (u16)(u >> 16);
}

DEV f32x4 mfma16(ushort8 a, ushort8 b, f32x4 c) {
    return __builtin_amdgcn_mfma_f32_16x16x32_bf16((bf16x8)a, (bf16x8)b, c, 0, 0, 0);
}

DEV void gload_lds16(const void* g, void* l) {   // async global->LDS, dst = base + lane*16
    __builtin_amdgcn_global_load_lds(
        (const __attribute__((address_space(1))) void*)g,
        (__attribute__((address_space(3))) void*)l, 16, 0, 0);
}

// ---------- fp32 -> bf16 elementwise ----------
__global__ void cvt_kernel(const float* __restrict__ in, u16* __restrict__ out, int n) {
    int i = (blockIdx.x * 256 + threadIdx.x) * 4;
    if (i >= n) return;
    float4 f = *(const float4*)(in + i);
    us4 o;
    o.x = f2bf(f.x); o.y = f2bf(f.y); o.z = f2bf(f.z); o.w = f2bf(f.w);
    *(us4*)(out + i) = o;
}

// ---------- fp32 [R][C] -> bf16 [C][R] (tiled, coalesced both sides) ----------
__global__ void transpose_cvt(const float* __restrict__ in, u16* __restrict__ out, int R, int C) {
    __shared__ u16 tile[64][72];
    int c0 = blockIdx.x << 6, r0 = blockIdx.y << 6;
    int tx = threadIdx.x & 63, ty = threadIdx.x >> 6;
    for (int i = 0; i < 64; i += 4) {
        int r = i + ty;
        tile[r][tx] = f2bf(in[(size_t)(r0 + r) * C + c0 + tx]);
    }
    __syncthreads();
    for (int i = 0; i < 64; i += 4) {
        int r = i + ty;
        out[(size_t)(c0 + r) * R + r0 + tx] = tile[tx][r];
    }
}

// ---------- 3x fused: Wq/Wk/Wv fp32 [512][4096] -> bf16 [4096][512], z selects src ----------
__global__ void transpose_cvt3(const float* __restrict__ in0, const float* __restrict__ in1,
                               const float* __restrict__ in2, u16* __restrict__ outbase) {
    __shared__ u16 tile[64][72];
    const float* in = (blockIdx.z == 0) ? in0 : (blockIdx.z == 1) ? in1 : in2;
    u16* out = outbase + (size_t)blockIdx.z * 2097152;   // 4 MB stride
    const int R = 512, C = 4096;
    int c0 = blockIdx.x << 6, r0 = blockIdx.y << 6;
    int tx = threadIdx.x & 63, ty = threadIdx.x >> 6;
    for (int i = 0; i < 64; i += 4) {
        int r = i + ty;
        tile[r][tx] = f2bf(in[(size_t)(r0 + r) * C + c0 + tx]);
    }
    __syncthreads();
    for (int i = 0; i < 64; i += 4) {
        int r = i + ty;
        out[(size_t)(c0 + r) * R + r0 + tx] = tile[tx][r];
    }
}

// ---------- bf16 [bh][2048][512] -> bf16 [bh][512][2048] ----------
__global__ void transpose_bh(const u16* __restrict__ in, u16* __restrict__ out) {
    __shared__ u16 tile[64][72];
    int bh = blockIdx.z;
    int d0 = blockIdx.x << 6, t0 = blockIdx.y << 6;
    int tx = threadIdx.x & 63, ty = threadIdx.x >> 6;
    const u16* src = in + (size_t)bh * 2048 * 512;
    u16* dst = out + (size_t)bh * 512 * 2048;
    for (int i = 0; i < 64; i += 4) {
        int r = i + ty;
        tile[r][tx] = src[(size_t)(t0 + r) * 512 + d0 + tx];
    }
    __syncthreads();
    for (int i = 0; i < 64; i += 4) {
        int r = i + ty;
        dst[(size_t)(d0 + r) * 2048 + t0 + tx] = tile[tx][r];
    }
}

// ---------- QKV GEMM (z-fused): C = xb @ W{q,k,v}t^T, 128x128 tile, Kc=512 ----------
// z = blockIdx.z selects weight + output slab; Q (z=0) pre-scaled by s2.
__launch_bounds__(256, 3)
__global__ void gemm_qkv(const u16* __restrict__ A, const u16* __restrict__ Btbase,
                         float s2, u16* __restrict__ outbase) {
    __shared__ u16 Asub[128 * 32];
    __shared__ u16 Bsub[128 * 32];
    const int Kc = 512;
    const u16* Bt = Btbase + (size_t)blockIdx.z * 2097152;     // 4 MB stride
    u16* out = outbase + (size_t)blockIdx.z * 16777216;        // 32 MB stride
    const float scale = (blockIdx.z == 0) ? s2 : 1.0f;

    const int tid = threadIdx.x, lane = tid & 63, wv = tid >> 6;
    const int bm = blockIdx.y << 7, bn = blockIdx.x << 7;
    const int wr = (wv >> 1) << 6, wc = (wv & 1) << 6;
    const int lr = lane & 15, hi = lane >> 4;

    f32x4 acc[4][4] = {};

    int off0 = (wv * 2048 + lane * 16) >> 1;
    int row0 = off0 >> 5, k0e = off0 & 31;
    int off1 = off0 + 512;
    int row1 = off1 >> 5, k1e = off1 & 31;

    const u16* Ag0 = A + (size_t)(bm + row0) * Kc + k0e;
    const u16* Ag1 = A + (size_t)(bm + row1) * Kc + k1e;
    const u16* Bg0 = Bt + (size_t)(bn + row0) * Kc + k0e;
    const u16* Bg1 = Bt + (size_t)(bn + row1) * Kc + k1e;

    for (int kk = 0; kk < Kc; kk += 32) {
        __syncthreads();
        gload_lds16(Ag0 + kk, &Asub[wv * 1024]);
        gload_lds16(Ag1 + kk, &Asub[wv * 1024 + 512]);
        gload_lds16(Bg0 + kk, &Bsub[wv * 1024]);
        gload_lds16(Bg1 + kk, &Bsub[wv * 1024 + 512]);
        __syncthreads();

        ushort8 a[4], b[4];
#pragma unroll
        for (int m = 0; m < 4; ++m)
            a[m] = *(const ushort8*)&Asub[(wr + m * 16 + lr) * 32 + hi * 8];
#pragma unroll
        for (int n = 0; n < 4; ++n)
            b[n] = *(const ushort8*)&Bsub[(wc + n * 16 + lr) * 32 + hi * 8];
#pragma unroll
        for (int m = 0; m < 4; ++m)
#pragma unroll
            for (int n = 0; n < 4; ++n)
                acc[m][n] = mfma16(a[m], b[n], acc[m][n]);
    }

#pragma unroll
    for (int m = 0; m < 4; ++m)
#pragma unroll
        for (int n = 0; n < 4; ++n)
#pragma unroll
            for (int r = 0; r < 4; ++r) {
                int row = bm + wr + m * 16 + hi * 4 + r;   // token index b*2048+t
                int col = bn + wc + n * 16 + lr;           // h*512+d
                float v = acc[m][n][r] * scale;
                size_t dst = ((size_t)((row >> 11) * 8 + (col >> 9)) * 2048 + (row & 2047)) * 512
                             + (col & 511);
                out[dst] = f2bf(v);
            }
}

// ---------- final GEMM: out[4096][512] = Ob[4096][4096] @ Wut[512][4096]^T + bu ----------
// BM=128, BN=64 -> grid (8,32) = 256 blocks (full chip; old 128x128 left half idle).
// 4 waves in 2x2; wave = 64 rows x 32 cols, acc[4][2]. fp32 output + bias.
__launch_bounds__(256, 3)
__global__ void gemm_final(const u16* __restrict__ A, const u16* __restrict__ Bt,
                           const float* __restrict__ bias, float* __restrict__ out, int Kc) {
    __shared__ u16 Asub[128 * 32];
    __shared__ u16 Bsub[64 * 32];
    const int tid = threadIdx.x, lane = tid & 63, wv = tid >> 6;
    const int bm = blockIdx.y << 7, bn = blockIdx.x << 6;
    const int wr = (wv >> 1) << 6, wc = (wv & 1) << 5;
    const int lr = lane & 15, hi = lane >> 4;

    f32x4 acc[4][2] = {};

    // staging: 12 segs x 1KB (A: 0-7, B: 8-11); wave wv stages segs wv*3..wv*3+2
    const u16* gsrc[3];
    u16* ldst[3];
#pragma unroll
    for (int j = 0; j < 3; ++j) {
        int g = wv * 3 + j;
        int off = g * 512 + lane * 8;
        if (g < 8) {
            int row = off >> 5, k = off & 31;
            gsrc[j] = A + (size_t)(bm + row) * Kc + k;
            ldst[j] = &Asub[g * 512];
        } else {
            int off2 = off - 4096;
            int row = off2 >> 5, k = off2 & 31;
            gsrc[j] = Bt + (size_t)(bn + row) * Kc + k;
            ldst[j] = &Bsub[(g - 8) * 512];
        }
    }

    for (int kk = 0; kk < Kc; kk += 32) {
        __syncthreads();
#pragma unroll
        for (int j = 0; j < 3; ++j) gload_lds16(gsrc[j] + kk, ldst[j]);
        __syncthreads();

        ushort8 a[4], b[2];
#pragma unroll
        for (int m = 0; m < 4; ++m)
            a[m] = *(const ushort8*)&Asub[(wr + m * 16 + lr) * 32 + hi * 8];
#pragma unroll
        for (int n = 0; n < 2; ++n)
            b[n] = *(const ushort8*)&Bsub[(wc + n * 16 + lr) * 32 + hi * 8];
#pragma unroll
        for (int m = 0; m < 4; ++m)
#pragma unroll
            for (int n = 0; n < 2; ++n)
                acc[m][n] = mfma16(a[m], b[n], acc[m][n]);
    }

#pragma unroll
    for (int m = 0; m < 4; ++m)
#pragma unroll
        for (int n = 0; n < 2; ++n)
#pragma unroll
            for (int r = 0; r < 4; ++r) {
                int row = bm + wr + m * 16 + hi * 4 + r;
                int col = bn + wc + n * 16 + lr;
                out[(size_t)row * 512 + col] = acc[m][n][r] + bias[col];
            }
}

// ---------- flash attention v8 (= v7 + vf-hoist inside post-barrier PV region) ----------
// T15 att[2] pipelining: iter t issues S(t) MFMAs, runs softmax(t-1) in their shadow,
// one barrier, then PV(t-1). K dbuf via global_load_lds (pre-swizzled source).
__launch_bounds__(512, 2)
__global__ void attn_kernel(const u16* __restrict__ Q, const u16* __restrict__ K,
                            const u16* __restrict__ Vt, u16* __restrict__ O) {
    __shared__ u16 Klds[2][32 * 512];            // 2 x 32KB, XOR-swizzled rows
    __shared__ u16 Plds[2][128 * 40];            // [q][32 keys + 8 pad]
    __shared__ __align__(16) float red[2][128];  // per-row alpha
    __shared__ __align__(16) float lred[128];    // final l
    __shared__ int rflag[2][8];                  // per-wave "some row rescaled"

    const int tid = threadIdx.x, lane = tid & 63, wv = tid >> 6;
    const int lr = lane & 15, hi = lane >> 4;
    const int qh = wv >> 2, ds = wv & 3;         // PV decomposition

    // XCD-chunked bijective swizzle: 256 blocks = 8 XCDs x 32; 2 bh per XCD chunk
    const int flat = blockIdx.x;
    const int nid = (flat & 7) * 32 + (flat >> 3);
    const int bh = nid >> 4;
    const int q0 = (nid & 15) << 7;

    // Q fragments (B-operand: col=lane&15 -> q-row wv*16+lr, k-slice hi*8..+8)
    ushort8 qf[16];
    {
        const char* Qg = (const char*)(Q + ((size_t)bh * 2048 + q0 + wv * 16 + lr) * 512) + hi * 16;
#pragma unroll
        for (int ks = 0; ks < 16; ++ks) qf[ks] = *(const ushort8*)(Qg + ks * 64);
    }

    f32x4 acc[4][8] = {};   // [q 16-block within 64-row half][d 16-frag within 128-wide slice]
    float mrun = -1e30f, lrun = 0.f;   // per-lane, q = wv*16+lr (replicated over hi), base-2

    const char* Kg = (const char*)(K + (size_t)bh * 2048 * 512);
    const char* Vg = (const char*)(Vt + (size_t)bh * 512 * 2048);

    // S-phase: 32 MFMAs into two chains (keys lr / lr+16), zero-started
    auto s_phase = [&](const char* Kb, f32x4& s0, f32x4& s1) {
        s0 = (f32x4){0.f, 0.f, 0.f, 0.f};
        s1 = (f32x4){0.f, 0.f, 0.f, 0.f};
#pragma unroll
        for (int ks = 0; ks < 16; ++ks) {
            int swz = (ks * 64 + hi * 16) ^ ((lr & 7) << 4);
            ushort8 kf0 = *(const ushort8*)(Kb + lr * 1024 + swz);
            ushort8 kf1 = *(const ushort8*)(Kb + (lr + 16) * 1024 + swz);
            s0 = mfma16(kf0, qf[ks], s0);
            s1 = mfma16(kf1, qf[ks], s1);
        }
    };

    // softmax on a finished S pair; writes P/alpha/flag into slot pcb
    auto softmax_store = [&](const f32x4& s0, const f32x4& s1, int pcb) {
        float mx = fmaxf(fmaxf(fmaxf(s0[0], s0[1]), fmaxf(s0[2], s0[3])),
                         fmaxf(fmaxf(s1[0], s1[1]), fmaxf(s1[2], s1[3])));
        mx = fmaxf(mx, __shfl_xor(mx, 16));
        mx = fmaxf(mx, __shfl_xor(mx, 32));
        float a = 1.0f;
        bool upd = false;
        if (mx > mrun + 11.5f) { a = exp2f(mrun - mx); mrun = mx; upd = true; }   // defer-max
        float p[8];
#pragma unroll
        for (int r = 0; r < 4; ++r) {
            p[r]     = exp2f(s0[r] - mrun);
            p[4 + r] = exp2f(s1[r] - mrun);
        }
        float ps = ((p[0] + p[1]) + (p[2] + p[3])) + ((p[4] + p[5]) + (p[6] + p[7]));
        ps += __shfl_xor(ps, 16);
        ps += __shfl_xor(ps, 32);
        lrun = lrun * a + ps;

        const int qr = wv * 16 + lr;
        char* Pb = (char*)&Plds[pcb][0] + qr * 80;
        uint2 w01, w23;
        w01.x = (unsigned)f2bf(p[0]) | ((unsigned)f2bf(p[1]) << 16);
        w01.y = (unsigned)f2bf(p[2]) | ((unsigned)f2bf(p[3]) << 16);
        w23.x = (unsigned)f2bf(p[4]) | ((unsigned)f2bf(p[5]) << 16);
        w23.y = (unsigned)f2bf(p[6]) | ((unsigned)f2bf(p[7]) << 16);
        *(uint2*)(Pb + hi * 8) = w01;
        *(uint2*)(Pb + 32 + hi * 8) = w23;
        if (hi == 0) red[pcb][qr] = a;
        if (lane == 0) rflag[pcb][wv] = __any(upd) ? 1 : 0;
    };

    // PV for tile whose P sits in slot pcb, V tile at key ktv.
    // vf loads issued FIRST in the post-barrier region (land under rescale/pf reads).
    auto pv_phase = [&](int pcb, int ktv) {
        ushort8 vf[8];
#pragma unroll
        for (int nf = 0; nf < 8; ++nf) {
            int d = ds * 128 + nf * 16 + lr;
            vf[nf] = *(const ushort8*)(Vg + (size_t)d * 4096 + (size_t)ktv * 2 + hi * 16);
        }
        int anyupd = rflag[pcb][0] | rflag[pcb][1] | rflag[pcb][2] | rflag[pcb][3]
                   | rflag[pcb][4] | rflag[pcb][5] | rflag[pcb][6] | rflag[pcb][7];
        if (anyupd) {
#pragma unroll
            for (int mf = 0; mf < 4; ++mf) {
                f32x4 a4 = *(const f32x4*)&red[pcb][qh * 64 + mf * 16 + hi * 4];
#pragma unroll
                for (int nf = 0; nf < 8; ++nf)
#pragma unroll
                    for (int r = 0; r < 4; ++r) acc[mf][nf][r] *= a4[r];
            }
        }
        ushort8 pf[4];
#pragma unroll
        for (int mf = 0; mf < 4; ++mf)
            pf[mf] = *(const ushort8*)((const char*)&Plds[pcb][0]
                                       + (qh * 64 + mf * 16 + lr) * 80 + hi * 16);
        __builtin_amdgcn_s_setprio(1);
#pragma unroll
        for (int nf = 0; nf < 8; ++nf)
#pragma unroll
            for (int mf = 0; mf < 4; ++mf) acc[mf][nf] = mfma16(pf[mf], vf[nf], acc[mf][nf]);
        __builtin_amdgcn_s_setprio(0);
    };

    auto prefetch_k = [&](int tt) {   // stage K(tt) into buf tt&1
        const char* Kgt = Kg + (size_t)tt * 32 * 1024;
#pragma unroll
        for (int r4 = 0; r4 < 4; ++r4) {
            int r = wv * 4 + r4;
            gload_lds16(Kgt + (size_t)r * 1024 + ((lane ^ (r & 7)) << 4),
                        &Klds[tt & 1][(size_t)r * 512]);
        }
    };

    f32x4 s0c, s1c, s0p, s1p;

    // prologue: K(0) -> buf0
    prefetch_k(0);
    __syncthreads();                       // K0 ready

    // peeled iter 0: prefetch K(1), S(0); no softmax/PV yet
    prefetch_k(1);
    s_phase((const char*)&Klds[0][0], s0c, s1c);
    __syncthreads();                       // K1 DMA drained; S(0) reads of buf0 done

    for (int t = 1; t < 64; ++t) {
        if (t + 1 < 64) prefetch_k(t + 1);       // -> buf (t+1)&1 (= buf read by S(t-1), done)

        s0p = s0c; s1p = s1c;                     // retire S(t-1) results
        s_phase((const char*)&Klds[t & 1][0], s0c, s1c);   // S(t) in flight...
        softmax_store(s0p, s1p, (t - 1) & 1);     // ...while softmax(t-1) runs on VALU

        __syncthreads();   // P(t-1)/alpha visible; K(t+1) drained; buf[t&1] reads done

        pv_phase((t - 1) & 1, (t - 1) << 5);
    }

    // epilogue: tile 63
    softmax_store(s0c, s1c, 1);
    __syncthreads();
    pv_phase(1, 63 << 5);

    // final l for all 128 rows -> LDS
    if (hi == 0) lred[wv * 16 + lr] = lrun;
    __syncthreads();

    const int b = bh >> 3, h = bh & 7;
#pragma unroll
    for (int mf = 0; mf < 4; ++mf) {
        f32x4 lv = *(const f32x4*)&lred[qh * 64 + mf * 16 + hi * 4];
        f32x4 inv;
#pragma unroll
        for (int r = 0; r < 4; ++r) inv[r] = 1.0f / lv[r];
#pragma unroll
        for (int nf = 0; nf < 8; ++nf) {
            int d = ds * 128 + nf * 16 + lr;
#pragma unroll
            for (int r = 0; r < 4; ++r) {
                int t = q0 + qh * 64 + mf * 16 + hi * 4 + r;
                O[((size_t)(b * 2048 + t)) * 4096 + h * 512 + d] = f2bf(acc[mf][nf][r] * inv[r]);
            }
        }
    }
}

// ---------- host ----------
extern "C" void kernel_launch(void* const* d_in, const int* in_sizes, int n_in,
                              void* d_out, int out_size, void* d_ws, size_t ws_size,
                              hipStream_t stream) {
    const float* x  = (const float*)d_in[0];
    const float* Wq = (const float*)d_in[1];
    const float* Wk = (const float*)d_in[2];
    const float* Wv = (const float*)d_in[3];
    const float* Wu = (const float*)d_in[4];
    const float* bu = (const float*)d_in[5];

    char* ws = (char*)d_ws;
    const size_t MB = 1ull << 20;
    u16* xb  = (u16*)(ws + 0);          // 4 MB  x as bf16 [4096][512]
    u16* Wqt = (u16*)(ws + 4 * MB);     // 3 x 4 MB: Wq^T,Wk^T,Wv^T bf16 [4096][512] contiguous
    u16* Wut = (u16*)(ws + 16 * MB);    // 4 MB  Wu^T bf16 [512][4096]
    u16* Qb  = (u16*)(ws + 20 * MB);    // 3 x 32 MB: Q,K,V [bh][t][d] contiguous (Q pre-scaled)
    u16* Vb  = (u16*)(ws + 84 * MB);
    u16* Vtb = (u16*)(ws + 116 * MB);   // 32 MB [bh][d][t]
    u16* Kb  = (u16*)(ws + 52 * MB);
    u16* Ob  = (u16*)(ws + 84 * MB);    // 32 MB [b*t][h*d]  (aliases Vb: V dead after transpose)

    cvt_kernel<<<2048, 256, 0, stream>>>(x, xb, 2 * 2048 * 512);
    transpose_cvt3<<<dim3(64, 8, 3), 256, 0, stream>>>(Wq, Wk, Wv, Wqt);
    transpose_cvt<<<dim3(8, 64), 256, 0, stream>>>(Wu, Wut, 4096, 512);

    // 512^-0.5 * log2(e): softmax runs in base-2 (exp2f), fold conversion into Q scale
    const float s2 = 0.06375871593f;
    gemm_qkv<<<dim3(32, 32, 3), 256, 0, stream>>>(xb, Wqt, s2, Qb);

    transpose_bh<<<dim3(8, 32, 16), 256, 0, stream>>>(Vb, Vtb);

    attn_kernel<<<256, 512, 0, stream>>>(Qb, Kb, Vtb, Ob);

    gemm_final<<<dim3(8, 32), 256, 0, stream>>>(Ob, Wut, bu, (float*)d_out, 4096);
}

// Round 9
// 469.108 us; speedup vs baseline: 1.1283x; 1.1283x over previous
//
#include <hip/hip_runtime.h>

typedef unsigned short u16;
typedef unsigned short ushort8 __attribute__((ext_vector_type(8)));
typedef unsigned short us4 __attribute__((ext_vector_type(4)));
typedef __bf16 bf16x8 __attribute__((ext_vector_type(8)));
typedef float f32x4 __attribute__((ext_vector_type(4)));

#define DEV static __device__ __forceinline__

// ---------- helpers ----------
DEV u16 f2bf(float f) {   // round-to-nearest-even f32 -> bf16
    unsigned int u = __builtin_bit_cast(unsigned int, f);
    u += 0x7FFFu + ((u >> 16) & 1u);
    return (u16)(u >> 16);
}

DEV f32x4 mfma16(ushort8 a, ushort8 b, f32x4 c) {
    return __builtin_amdgcn_mfma_f32_16x16x32_bf16((bf16x8)a, (bf16x8)b, c, 0, 0, 0);
}

DEV void gload_lds16(const void* g, void* l) {   // async global->LDS, dst = base + lane*16
    __builtin_amdgcn_global_load_lds(
        (const __attribute__((address_space(1))) void*)g,
        (__attribute__((address_space(3))) void*)l, 16, 0, 0);
}

// ---------- fp32 -> bf16 elementwise ----------
__global__ void cvt_kernel(const float* __restrict__ in, u16* __restrict__ out, int n) {
    int i = (blockIdx.x * 256 + threadIdx.x) * 4;
    if (i >= n) return;
    float4 f = *(const float4*)(in + i);
    us4 o;
    o.x = f2bf(f.x); o.y = f2bf(f.y); o.z = f2bf(f.z); o.w = f2bf(f.w);
    *(us4*)(out + i) = o;
}

// ---------- fp32 [R][C] -> bf16 [C][R] (tiled, coalesced both sides) ----------
__global__ void transpose_cvt(const float* __restrict__ in, u16* __restrict__ out, int R, int C) {
    __shared__ u16 tile[64][72];
    int c0 = blockIdx.x << 6, r0 = blockIdx.y << 6;
    int tx = threadIdx.x & 63, ty = threadIdx.x >> 6;
    for (int i = 0; i < 64; i += 4) {
        int r = i + ty;
        tile[r][tx] = f2bf(in[(size_t)(r0 + r) * C + c0 + tx]);
    }
    __syncthreads();
    for (int i = 0; i < 64; i += 4) {
        int r = i + ty;
        out[(size_t)(c0 + r) * R + r0 + tx] = tile[tx][r];
    }
}

// ---------- 3x fused: Wq/Wk/Wv fp32 [512][4096] -> bf16 [4096][512], z selects src ----------
__global__ void transpose_cvt3(const float* __restrict__ in0, const float* __restrict__ in1,
                               const float* __restrict__ in2, u16* __restrict__ outbase) {
    __shared__ u16 tile[64][72];
    const float* in = (blockIdx.z == 0) ? in0 : (blockIdx.z == 1) ? in1 : in2;
    u16* out = outbase + (size_t)blockIdx.z * 2097152;   // 4 MB stride
    const int R = 512, C = 4096;
    int c0 = blockIdx.x << 6, r0 = blockIdx.y << 6;
    int tx = threadIdx.x & 63, ty = threadIdx.x >> 6;
    for (int i = 0; i < 64; i += 4) {
        int r = i + ty;
        tile[r][tx] = f2bf(in[(size_t)(r0 + r) * C + c0 + tx]);
    }
    __syncthreads();
    for (int i = 0; i < 64; i += 4) {
        int r = i + ty;
        out[(size_t)(c0 + r) * R + r0 + tx] = tile[tx][r];
    }
}

// ---------- bf16 [bh][2048][512] -> bf16 [bh][512][2048] ----------
__global__ void transpose_bh(const u16* __restrict__ in, u16* __restrict__ out) {
    __shared__ u16 tile[64][72];
    int bh = blockIdx.z;
    int d0 = blockIdx.x << 6, t0 = blockIdx.y << 6;
    int tx = threadIdx.x & 63, ty = threadIdx.x >> 6;
    const u16* src = in + (size_t)bh * 2048 * 512;
    u16* dst = out + (size_t)bh * 512 * 2048;
    for (int i = 0; i < 64; i += 4) {
        int r = i + ty;
        tile[r][tx] = src[(size_t)(t0 + r) * 512 + d0 + tx];
    }
    __syncthreads();
    for (int i = 0; i < 64; i += 4) {
        int r = i + ty;
        dst[(size_t)(d0 + r) * 2048 + t0 + tx] = tile[tx][r];
    }
}

// ---------- QKV GEMM (z-fused): C = xb @ W{q,k,v}t^T, 128x128 tile, Kc=512 ----------
// z = blockIdx.z selects weight + output slab; Q (z=0) pre-scaled by s2.
__launch_bounds__(256, 3)
__global__ void gemm_qkv(const u16* __restrict__ A, const u16* __restrict__ Btbase,
                         float s2, u16* __restrict__ outbase) {
    __shared__ u16 Asub[128 * 32];
    __shared__ u16 Bsub[128 * 32];
    const int Kc = 512;
    const u16* Bt = Btbase + (size_t)blockIdx.z * 2097152;     // 4 MB stride
    u16* out = outbase + (size_t)blockIdx.z * 16777216;        // 32 MB stride
    const float scale = (blockIdx.z == 0) ? s2 : 1.0f;

    const int tid = threadIdx.x, lane = tid & 63, wv = tid >> 6;
    const int bm = blockIdx.y << 7, bn = blockIdx.x << 7;
    const int wr = (wv >> 1) << 6, wc = (wv & 1) << 6;
    const int lr = lane & 15, hi = lane >> 4;

    f32x4 acc[4][4] = {};

    int off0 = (wv * 2048 + lane * 16) >> 1;
    int row0 = off0 >> 5, k0e = off0 & 31;
    int off1 = off0 + 512;
    int row1 = off1 >> 5, k1e = off1 & 31;

    const u16* Ag0 = A + (size_t)(bm + row0) * Kc + k0e;
    const u16* Ag1 = A + (size_t)(bm + row1) * Kc + k1e;
    const u16* Bg0 = Bt + (size_t)(bn + row0) * Kc + k0e;
    const u16* Bg1 = Bt + (size_t)(bn + row1) * Kc + k1e;

    for (int kk = 0; kk < Kc; kk += 32) {
        __syncthreads();
        gload_lds16(Ag0 + kk, &Asub[wv * 1024]);
        gload_lds16(Ag1 + kk, &Asub[wv * 1024 + 512]);
        gload_lds16(Bg0 + kk, &Bsub[wv * 1024]);
        gload_lds16(Bg1 + kk, &Bsub[wv * 1024 + 512]);
        __syncthreads();

        ushort8 a[4], b[4];
#pragma unroll
        for (int m = 0; m < 4; ++m)
            a[m] = *(const ushort8*)&Asub[(wr + m * 16 + lr) * 32 + hi * 8];
#pragma unroll
        for (int n = 0; n < 4; ++n)
            b[n] = *(const ushort8*)&Bsub[(wc + n * 16 + lr) * 32 + hi * 8];
#pragma unroll
        for (int m = 0; m < 4; ++m)
#pragma unroll
            for (int n = 0; n < 4; ++n)
                acc[m][n] = mfma16(a[m], b[n], acc[m][n]);
    }

#pragma unroll
    for (int m = 0; m < 4; ++m)
#pragma unroll
        for (int n = 0; n < 4; ++n)
#pragma unroll
            for (int r = 0; r < 4; ++r) {
                int row = bm + wr + m * 16 + hi * 4 + r;   // token index b*2048+t
                int col = bn + wc + n * 16 + lr;           // h*512+d
                float v = acc[m][n][r] * scale;
                size_t dst = ((size_t)((row >> 11) * 8 + (col >> 9)) * 2048 + (row & 2047)) * 512
                             + (col & 511);
                out[dst] = f2bf(v);
            }
}

// ---------- final GEMM: out[4096][512] = Ob[4096][4096] @ Wut[512][4096]^T + bu ----------
// BM=128, BN=64 -> grid (8,32) = 256 blocks (full chip).
__launch_bounds__(256, 3)
__global__ void gemm_final(const u16* __restrict__ A, const u16* __restrict__ Bt,
                           const float* __restrict__ bias, float* __restrict__ out, int Kc) {
    __shared__ u16 Asub[128 * 32];
    __shared__ u16 Bsub[64 * 32];
    const int tid = threadIdx.x, lane = tid & 63, wv = tid >> 6;
    const int bm = blockIdx.y << 7, bn = blockIdx.x << 6;
    const int wr = (wv >> 1) << 6, wc = (wv & 1) << 5;
    const int lr = lane & 15, hi = lane >> 4;

    f32x4 acc[4][2] = {};

    // staging: 12 segs x 1KB (A: 0-7, B: 8-11); wave wv stages segs wv*3..wv*3+2
    const u16* gsrc[3];
    u16* ldst[3];
#pragma unroll
    for (int j = 0; j < 3; ++j) {
        int g = wv * 3 + j;
        int off = g * 512 + lane * 8;
        if (g < 8) {
            int row = off >> 5, k = off & 31;
            gsrc[j] = A + (size_t)(bm + row) * Kc + k;
            ldst[j] = &Asub[g * 512];
        } else {
            int off2 = off - 4096;
            int row = off2 >> 5, k = off2 & 31;
            gsrc[j] = Bt + (size_t)(bn + row) * Kc + k;
            ldst[j] = &Bsub[(g - 8) * 512];
        }
    }

    for (int kk = 0; kk < Kc; kk += 32) {
        __syncthreads();
#pragma unroll
        for (int j = 0; j < 3; ++j) gload_lds16(gsrc[j] + kk, ldst[j]);
        __syncthreads();

        ushort8 a[4], b[2];
#pragma unroll
        for (int m = 0; m < 4; ++m)
            a[m] = *(const ushort8*)&Asub[(wr + m * 16 + lr) * 32 + hi * 8];
#pragma unroll
        for (int n = 0; n < 2; ++n)
            b[n] = *(const ushort8*)&Bsub[(wc + n * 16 + lr) * 32 + hi * 8];
#pragma unroll
        for (int m = 0; m < 4; ++m)
#pragma unroll
            for (int n = 0; n < 2; ++n)
                acc[m][n] = mfma16(a[m], b[n], acc[m][n]);
    }

#pragma unroll
    for (int m = 0; m < 4; ++m)
#pragma unroll
        for (int n = 0; n < 2; ++n)
#pragma unroll
            for (int r = 0; r < 4; ++r) {
                int row = bm + wr + m * 16 + hi * 4 + r;
                int col = bn + wc + n * 16 + lr;
                out[(size_t)row * 512 + col] = acc[m][n][r] + bias[col];
            }
}

// ---------- flash attention v9 (= v7 attn, verbatim: inline per-nf V loads) ----------
// T15 att[2] pipelining: iter t issues S(t) MFMAs, runs softmax(t-1) in their shadow,
// one barrier, then PV(t-1). K dbuf via global_load_lds (pre-swizzled source).
// V loads stay INLINE in the nf loop: compiler rolls load(nf+1) under MFMAs(nf)
// (v3 pre-barrier hoist and v8 post-barrier batch-hoist both regressed; do not move).
__launch_bounds__(512, 2)
__global__ void attn_kernel(const u16* __restrict__ Q, const u16* __restrict__ K,
                            const u16* __restrict__ Vt, u16* __restrict__ O) {
    __shared__ u16 Klds[2][32 * 512];            // 2 x 32KB, XOR-swizzled rows
    __shared__ u16 Plds[2][128 * 40];            // [q][32 keys + 8 pad]
    __shared__ __align__(16) float red[2][128];  // per-row alpha
    __shared__ __align__(16) float lred[128];    // final l
    __shared__ int rflag[2][8];                  // per-wave "some row rescaled"

    const int tid = threadIdx.x, lane = tid & 63, wv = tid >> 6;
    const int lr = lane & 15, hi = lane >> 4;
    const int qh = wv >> 2, ds = wv & 3;         // PV decomposition

    // XCD-chunked bijective swizzle: 256 blocks = 8 XCDs x 32; 2 bh per XCD chunk
    const int flat = blockIdx.x;
    const int nid = (flat & 7) * 32 + (flat >> 3);
    const int bh = nid >> 4;
    const int q0 = (nid & 15) << 7;

    // Q fragments (B-operand: col=lane&15 -> q-row wv*16+lr, k-slice hi*8..+8)
    ushort8 qf[16];
    {
        const char* Qg = (const char*)(Q + ((size_t)bh * 2048 + q0 + wv * 16 + lr) * 512) + hi * 16;
#pragma unroll
        for (int ks = 0; ks < 16; ++ks) qf[ks] = *(const ushort8*)(Qg + ks * 64);
    }

    f32x4 acc[4][8] = {};   // [q 16-block within 64-row half][d 16-frag within 128-wide slice]
    float mrun = -1e30f, lrun = 0.f;   // per-lane, q = wv*16+lr (replicated over hi), base-2

    const char* Kg = (const char*)(K + (size_t)bh * 2048 * 512);
    const char* Vg = (const char*)(Vt + (size_t)bh * 512 * 2048);

    // S-phase: 32 MFMAs into two chains (keys lr / lr+16), zero-started
    auto s_phase = [&](const char* Kb, f32x4& s0, f32x4& s1) {
        s0 = (f32x4){0.f, 0.f, 0.f, 0.f};
        s1 = (f32x4){0.f, 0.f, 0.f, 0.f};
#pragma unroll
        for (int ks = 0; ks < 16; ++ks) {
            int swz = (ks * 64 + hi * 16) ^ ((lr & 7) << 4);
            ushort8 kf0 = *(const ushort8*)(Kb + lr * 1024 + swz);
            ushort8 kf1 = *(const ushort8*)(Kb + (lr + 16) * 1024 + swz);
            s0 = mfma16(kf0, qf[ks], s0);
            s1 = mfma16(kf1, qf[ks], s1);
        }
    };

    // softmax on a finished S pair; writes P/alpha/flag into slot pcb
    auto softmax_store = [&](const f32x4& s0, const f32x4& s1, int pcb) {
        float mx = fmaxf(fmaxf(fmaxf(s0[0], s0[1]), fmaxf(s0[2], s0[3])),
                         fmaxf(fmaxf(s1[0], s1[1]), fmaxf(s1[2], s1[3])));
        mx = fmaxf(mx, __shfl_xor(mx, 16));
        mx = fmaxf(mx, __shfl_xor(mx, 32));
        float a = 1.0f;
        bool upd = false;
        if (mx > mrun + 11.5f) { a = exp2f(mrun - mx); mrun = mx; upd = true; }   // defer-max
        float p[8];
#pragma unroll
        for (int r = 0; r < 4; ++r) {
            p[r]     = exp2f(s0[r] - mrun);
            p[4 + r] = exp2f(s1[r] - mrun);
        }
        float ps = ((p[0] + p[1]) + (p[2] + p[3])) + ((p[4] + p[5]) + (p[6] + p[7]));
        ps += __shfl_xor(ps, 16);
        ps += __shfl_xor(ps, 32);
        lrun = lrun * a + ps;

        const int qr = wv * 16 + lr;
        char* Pb = (char*)&Plds[pcb][0] + qr * 80;
        uint2 w01, w23;
        w01.x = (unsigned)f2bf(p[0]) | ((unsigned)f2bf(p[1]) << 16);
        w01.y = (unsigned)f2bf(p[2]) | ((unsigned)f2bf(p[3]) << 16);
        w23.x = (unsigned)f2bf(p[4]) | ((unsigned)f2bf(p[5]) << 16);
        w23.y = (unsigned)f2bf(p[6]) | ((unsigned)f2bf(p[7]) << 16);
        *(uint2*)(Pb + hi * 8) = w01;
        *(uint2*)(Pb + 32 + hi * 8) = w23;
        if (hi == 0) red[pcb][qr] = a;
        if (lane == 0) rflag[pcb][wv] = __any(upd) ? 1 : 0;
    };

    // rescale (defer-max gated) + PV for tile whose P sits in slot pcb, V tile at key ktv
    auto pv_phase = [&](int pcb, int ktv) {
        int anyupd = rflag[pcb][0] | rflag[pcb][1] | rflag[pcb][2] | rflag[pcb][3]
                   | rflag[pcb][4] | rflag[pcb][5] | rflag[pcb][6] | rflag[pcb][7];
        if (anyupd) {
#pragma unroll
            for (int mf = 0; mf < 4; ++mf) {
                f32x4 a4 = *(const f32x4*)&red[pcb][qh * 64 + mf * 16 + hi * 4];
#pragma unroll
                for (int nf = 0; nf < 8; ++nf)
#pragma unroll
                    for (int r = 0; r < 4; ++r) acc[mf][nf][r] *= a4[r];
            }
        }
        ushort8 pf[4];
#pragma unroll
        for (int mf = 0; mf < 4; ++mf)
            pf[mf] = *(const ushort8*)((const char*)&Plds[pcb][0]
                                       + (qh * 64 + mf * 16 + lr) * 80 + hi * 16);
        __builtin_amdgcn_s_setprio(1);
#pragma unroll
        for (int nf = 0; nf < 8; ++nf) {
            int d = ds * 128 + nf * 16 + lr;
            ushort8 vf = *(const ushort8*)(Vg + (size_t)d * 4096 + (size_t)ktv * 2 + hi * 16);
#pragma unroll
            for (int mf = 0; mf < 4; ++mf) acc[mf][nf] = mfma16(pf[mf], vf, acc[mf][nf]);
        }
        __builtin_amdgcn_s_setprio(0);
    };

    auto prefetch_k = [&](int tt) {   // stage K(tt) into buf tt&1
        const char* Kgt = Kg + (size_t)tt * 32 * 1024;
#pragma unroll
        for (int r4 = 0; r4 < 4; ++r4) {
            int r = wv * 4 + r4;
            gload_lds16(Kgt + (size_t)r * 1024 + ((lane ^ (r & 7)) << 4),
                        &Klds[tt & 1][(size_t)r * 512]);
        }
    };

    f32x4 s0c, s1c, s0p, s1p;

    // prologue: K(0) -> buf0
    prefetch_k(0);
    __syncthreads();                       // K0 ready

    // peeled iter 0: prefetch K(1), S(0); no softmax/PV yet
    prefetch_k(1);
    s_phase((const char*)&Klds[0][0], s0c, s1c);
    __syncthreads();                       // K1 DMA drained; S(0) reads of buf0 done

    for (int t = 1; t < 64; ++t) {
        if (t + 1 < 64) prefetch_k(t + 1);       // -> buf (t+1)&1 (= buf read by S(t-1), done)

        s0p = s0c; s1p = s1c;                     // retire S(t-1) results
        s_phase((const char*)&Klds[t & 1][0], s0c, s1c);   // S(t) in flight...
        softmax_store(s0p, s1p, (t - 1) & 1);     // ...while softmax(t-1) runs on VALU

        __syncthreads();   // P(t-1)/alpha visible; K(t+1) drained; buf[t&1] reads done

        pv_phase((t - 1) & 1, (t - 1) << 5);
    }

    // epilogue: tile 63
    softmax_store(s0c, s1c, 1);
    __syncthreads();
    pv_phase(1, 63 << 5);

    // final l for all 128 rows -> LDS
    if (hi == 0) lred[wv * 16 + lr] = lrun;
    __syncthreads();

    const int b = bh >> 3, h = bh & 7;
#pragma unroll
    for (int mf = 0; mf < 4; ++mf) {
        f32x4 lv = *(const f32x4*)&lred[qh * 64 + mf * 16 + hi * 4];
        f32x4 inv;
#pragma unroll
        for (int r = 0; r < 4; ++r) inv[r] = 1.0f / lv[r];
#pragma unroll
        for (int nf = 0; nf < 8; ++nf) {
            int d = ds * 128 + nf * 16 + lr;
#pragma unroll
            for (int r = 0; r < 4; ++r) {
                int t = q0 + qh * 64 + mf * 16 + hi * 4 + r;
                O[((size_t)(b * 2048 + t)) * 4096 + h * 512 + d] = f2bf(acc[mf][nf][r] * inv[r]);
            }
        }
    }
}

// ---------- host ----------
extern "C" void kernel_launch(void* const* d_in, const int* in_sizes, int n_in,
                              void* d_out, int out_size, void* d_ws, size_t ws_size,
                              hipStream_t stream) {
    const float* x  = (const float*)d_in[0];
    const float* Wq = (const float*)d_in[1];
    const float* Wk = (const float*)d_in[2];
    const float* Wv = (const float*)d_in[3];
    const float* Wu = (const float*)d_in[4];
    const float* bu = (const float*)d_in[5];

    char* ws = (char*)d_ws;
    const size_t MB = 1ull << 20;
    u16* xb  = (u16*)(ws + 0);          // 4 MB  x as bf16 [4096][512]
    u16* Wqt = (u16*)(ws + 4 * MB);     // 3 x 4 MB: Wq^T,Wk^T,Wv^T bf16 [4096][512] contiguous
    u16* Wut = (u16*)(ws + 16 * MB);    // 4 MB  Wu^T bf16 [512][4096]
    u16* Qb  = (u16*)(ws + 20 * MB);    // 3 x 32 MB: Q,K,V [bh][t][d] contiguous (Q pre-scaled)
    u16* Kb  = (u16*)(ws + 52 * MB);
    u16* Vb  = (u16*)(ws + 84 * MB);
    u16* Vtb = (u16*)(ws + 116 * MB);   // 32 MB [bh][d][t]
    u16* Ob  = (u16*)(ws + 84 * MB);    // 32 MB [b*t][h*d]  (aliases Vb: V dead after transpose)

    cvt_kernel<<<2048, 256, 0, stream>>>(x, xb, 2 * 2048 * 512);
    transpose_cvt3<<<dim3(64, 8, 3), 256, 0, stream>>>(Wq, Wk, Wv, Wqt);
    transpose_cvt<<<dim3(8, 64), 256, 0, stream>>>(Wu, Wut, 4096, 512);

    // 512^-0.5 * log2(e): softmax runs in base-2 (exp2f), fold conversion into Q scale
    const float s2 = 0.06375871593f;
    gemm_qkv<<<dim3(32, 32, 3), 256, 0, stream>>>(xb, Wqt, s2, Qb);

    transpose_bh<<<dim3(8, 32, 16), 256, 0, stream>>>(Vb, Vtb);

    attn_kernel<<<256, 512, 0, stream>>>(Qb, Kb, Vtb, Ob);

    gemm_final<<<dim3(8, 32), 256, 0, stream>>>(Ob, Wut, bu, (float*)d_out, 4096);
}

// Round 10
// 456.913 us; speedup vs baseline: 1.1584x; 1.0267x over previous
//
#include <hip/hip_runtime.h>

typedef unsigned short u16;
typedef unsigned short ushort8 __attribute__((ext_vector_type(8)));
typedef unsigned short us4 __attribute__((ext_vector_type(4)));
typedef __bf16 bf16x8 __attribute__((ext_vector_type(8)));
typedef float f32x4 __attribute__((ext_vector_type(4)));

#define DEV static __device__ __forceinline__

// ---------- helpers ----------
DEV u16 f2bf(float f) {   // round-to-nearest-even f32 -> bf16
    unsigned int u = __builtin_bit_cast(unsigned int, f);
    u += 0x7FFFu + ((u >> 16) & 1u);
    return (u16)(u >> 16);
}

DEV f32x4 mfma16(ushort8 a, ushort8 b, f32x4 c) {
    return __builtin_amdgcn_mfma_f32_16x16x32_bf16((bf16x8)a, (bf16x8)b, c, 0, 0, 0);
}

DEV void gload_lds16(const void* g, void* l) {   // async global->LDS, dst = base + lane*16
    __builtin_amdgcn_global_load_lds(
        (const __attribute__((address_space(1))) void*)g,
        (__attribute__((address_space(3))) void*)l, 16, 0, 0);
}

// ---------- fused prep: x cvt + Wq/Wk/Wv transpose + Wu transpose (one launch) ----------
// flat grid 4096: [0,2048) x->bf16; [2048,3584) W{q,k,v}^T (z = (bid-2048)>>9);
// [3584,4096) Wu^T. All branches block-uniform, 256 threads.
__global__ void prep_kernel(const float* __restrict__ x,
                            const float* __restrict__ Wq, const float* __restrict__ Wk,
                            const float* __restrict__ Wv, const float* __restrict__ Wu,
                            u16* __restrict__ xb, u16* __restrict__ Wqt, u16* __restrict__ Wut) {
    __shared__ u16 tile[64][72];
    const int bid = blockIdx.x;

    if (bid < 2048) {                              // x fp32 -> bf16, vectorized
        int i = (bid * 256 + threadIdx.x) * 4;
        float4 f = *(const float4*)(x + i);
        us4 o;
        o.x = f2bf(f.x); o.y = f2bf(f.y); o.z = f2bf(f.z); o.w = f2bf(f.w);
        *(us4*)(xb + i) = o;
        return;
    }

    const float* in;
    u16* out;
    int R, C, c0, r0;
    if (bid < 3584) {                              // Wq/Wk/Wv [512][4096] -> ^T bf16
        int j = bid - 2048;
        int z = j >> 9, rem = j & 511;
        in = (z == 0) ? Wq : (z == 1) ? Wk : Wv;
        out = Wqt + (size_t)z * 2097152;           // 4 MB stride
        R = 512; C = 4096;
        c0 = (rem & 63) << 6; r0 = (rem >> 6) << 6;
    } else {                                       // Wu [4096][512] -> ^T bf16
        int k = bid - 3584;
        in = Wu; out = Wut;
        R = 4096; C = 512;
        c0 = (k & 7) << 6; r0 = (k >> 3) << 6;
    }
    int tx = threadIdx.x & 63, ty = threadIdx.x >> 6;
    for (int i = 0; i < 64; i += 4) {
        int r = i + ty;
        tile[r][tx] = f2bf(in[(size_t)(r0 + r) * C + c0 + tx]);
    }
    __syncthreads();
    for (int i = 0; i < 64; i += 4) {
        int r = i + ty;
        out[(size_t)(c0 + r) * R + r0 + tx] = tile[tx][r];
    }
}

// ---------- QKV GEMM (z-fused): C = xb @ W{q,k,v}t^T, 128x128 tile, Kc=512 ----------
// z selects weight + output; Q (z=0) pre-scaled by s2.
// z==2 (V) stores DIRECTLY TRANSPOSED to Vtb [bh][d][t]: the 4 r-values are 4
// consecutive tokens at fixed d -> one packed 8B store (kills transpose_bh).
__launch_bounds__(256, 3)
__global__ void gemm_qkv(const u16* __restrict__ A, const u16* __restrict__ Btbase,
                         float s2, u16* __restrict__ outbase, u16* __restrict__ vtb) {
    __shared__ u16 Asub[128 * 32];
    __shared__ u16 Bsub[128 * 32];
    const int Kc = 512;
    const u16* Bt = Btbase + (size_t)blockIdx.z * 2097152;     // 4 MB stride
    u16* out = outbase + (size_t)blockIdx.z * 16777216;        // 32 MB stride (z=0,1)
    const float scale = (blockIdx.z == 0) ? s2 : 1.0f;

    const int tid = threadIdx.x, lane = tid & 63, wv = tid >> 6;
    const int bm = blockIdx.y << 7, bn = blockIdx.x << 7;
    const int wr = (wv >> 1) << 6, wc = (wv & 1) << 6;
    const int lr = lane & 15, hi = lane >> 4;

    f32x4 acc[4][4] = {};

    int off0 = (wv * 2048 + lane * 16) >> 1;
    int row0 = off0 >> 5, k0e = off0 & 31;
    int off1 = off0 + 512;
    int row1 = off1 >> 5, k1e = off1 & 31;

    const u16* Ag0 = A + (size_t)(bm + row0) * Kc + k0e;
    const u16* Ag1 = A + (size_t)(bm + row1) * Kc + k1e;
    const u16* Bg0 = Bt + (size_t)(bn + row0) * Kc + k0e;
    const u16* Bg1 = Bt + (size_t)(bn + row1) * Kc + k1e;

    for (int kk = 0; kk < Kc; kk += 32) {
        __syncthreads();
        gload_lds16(Ag0 + kk, &Asub[wv * 1024]);
        gload_lds16(Ag1 + kk, &Asub[wv * 1024 + 512]);
        gload_lds16(Bg0 + kk, &Bsub[wv * 1024]);
        gload_lds16(Bg1 + kk, &Bsub[wv * 1024 + 512]);
        __syncthreads();

        ushort8 a[4], b[4];
#pragma unroll
        for (int m = 0; m < 4; ++m)
            a[m] = *(const ushort8*)&Asub[(wr + m * 16 + lr) * 32 + hi * 8];
#pragma unroll
        for (int n = 0; n < 4; ++n)
            b[n] = *(const ushort8*)&Bsub[(wc + n * 16 + lr) * 32 + hi * 8];
#pragma unroll
        for (int m = 0; m < 4; ++m)
#pragma unroll
            for (int n = 0; n < 4; ++n)
                acc[m][n] = mfma16(a[m], b[n], acc[m][n]);
    }

    if (blockIdx.z == 2) {
        // V: packed-transposed store to Vtb[bh][d][t]
#pragma unroll
        for (int m = 0; m < 4; ++m)
#pragma unroll
            for (int n = 0; n < 4; ++n) {
                int row0v = bm + wr + m * 16 + hi * 4;     // token = b*2048 + t0 (t0 % 4 == 0)
                int col   = bn + wc + n * 16 + lr;         // h*512 + d
                int b = row0v >> 11, t0 = row0v & 2047;
                int h = col >> 9, d = col & 511;
                us4 pk;
#pragma unroll
                for (int r = 0; r < 4; ++r) pk[r] = f2bf(acc[m][n][r]);
                *(us4*)&vtb[(((size_t)(b * 8 + h) * 512 + d) << 11) + t0] = pk;
            }
    } else {
#pragma unroll
        for (int m = 0; m < 4; ++m)
#pragma unroll
            for (int n = 0; n < 4; ++n)
#pragma unroll
                for (int r = 0; r < 4; ++r) {
                    int row = bm + wr + m * 16 + hi * 4 + r;   // token index b*2048+t
                    int col = bn + wc + n * 16 + lr;           // h*512+d
                    float v = acc[m][n][r] * scale;
                    size_t dst = ((size_t)((row >> 11) * 8 + (col >> 9)) * 2048 + (row & 2047)) * 512
                                 + (col & 511);
                    out[dst] = f2bf(v);
                }
    }
}

// ---------- final GEMM: out[4096][512] = Ob[4096][4096] @ Wut[512][4096]^T + bu ----------
// BM=128, BN=64 -> grid (8,32) = 256 blocks (full chip).
__launch_bounds__(256, 3)
__global__ void gemm_final(const u16* __restrict__ A, const u16* __restrict__ Bt,
                           const float* __restrict__ bias, float* __restrict__ out, int Kc) {
    __shared__ u16 Asub[128 * 32];
    __shared__ u16 Bsub[64 * 32];
    const int tid = threadIdx.x, lane = tid & 63, wv = tid >> 6;
    const int bm = blockIdx.y << 7, bn = blockIdx.x << 6;
    const int wr = (wv >> 1) << 6, wc = (wv & 1) << 5;
    const int lr = lane & 15, hi = lane >> 4;

    f32x4 acc[4][2] = {};

    // staging: 12 segs x 1KB (A: 0-7, B: 8-11); wave wv stages segs wv*3..wv*3+2
    const u16* gsrc[3];
    u16* ldst[3];
#pragma unroll
    for (int j = 0; j < 3; ++j) {
        int g = wv * 3 + j;
        int off = g * 512 + lane * 8;
        if (g < 8) {
            int row = off >> 5, k = off & 31;
            gsrc[j] = A + (size_t)(bm + row) * Kc + k;
            ldst[j] = &Asub[g * 512];
        } else {
            int off2 = off - 4096;
            int row = off2 >> 5, k = off2 & 31;
            gsrc[j] = Bt + (size_t)(bn + row) * Kc + k;
            ldst[j] = &Bsub[(g - 8) * 512];
        }
    }

    for (int kk = 0; kk < Kc; kk += 32) {
        __syncthreads();
#pragma unroll
        for (int j = 0; j < 3; ++j) gload_lds16(gsrc[j] + kk, ldst[j]);
        __syncthreads();

        ushort8 a[4], b[2];
#pragma unroll
        for (int m = 0; m < 4; ++m)
            a[m] = *(const ushort8*)&Asub[(wr + m * 16 + lr) * 32 + hi * 8];
#pragma unroll
        for (int n = 0; n < 2; ++n)
            b[n] = *(const ushort8*)&Bsub[(wc + n * 16 + lr) * 32 + hi * 8];
#pragma unroll
        for (int m = 0; m < 4; ++m)
#pragma unroll
            for (int n = 0; n < 2; ++n)
                acc[m][n] = mfma16(a[m], b[n], acc[m][n]);
    }

#pragma unroll
    for (int m = 0; m < 4; ++m)
#pragma unroll
        for (int n = 0; n < 2; ++n)
#pragma unroll
            for (int r = 0; r < 4; ++r) {
                int row = bm + wr + m * 16 + hi * 4 + r;
                int col = bn + wc + n * 16 + lr;
                out[(size_t)row * 512 + col] = acc[m][n][r] + bias[col];
            }
}

// ---------- flash attention (v7 attn, FROZEN: inline per-nf V loads) ----------
// T15 att[2] pipelining: iter t issues S(t) MFMAs, runs softmax(t-1) in their shadow,
// one barrier, then PV(t-1). K dbuf via global_load_lds (pre-swizzled source).
// V loads stay INLINE in the nf loop (v3 pre-barrier hoist and v8 batch-hoist both
// regressed; compiler rolls load(nf+1) under MFMAs(nf) — do not move).
__launch_bounds__(512, 2)
__global__ void attn_kernel(const u16* __restrict__ Q, const u16* __restrict__ K,
                            const u16* __restrict__ Vt, u16* __restrict__ O) {
    __shared__ u16 Klds[2][32 * 512];            // 2 x 32KB, XOR-swizzled rows
    __shared__ u16 Plds[2][128 * 40];            // [q][32 keys + 8 pad]
    __shared__ __align__(16) float red[2][128];  // per-row alpha
    __shared__ __align__(16) float lred[128];    // final l
    __shared__ int rflag[2][8];                  // per-wave "some row rescaled"

    const int tid = threadIdx.x, lane = tid & 63, wv = tid >> 6;
    const int lr = lane & 15, hi = lane >> 4;
    const int qh = wv >> 2, ds = wv & 3;         // PV decomposition

    // XCD-chunked bijective swizzle: 256 blocks = 8 XCDs x 32; 2 bh per XCD chunk
    const int flat = blockIdx.x;
    const int nid = (flat & 7) * 32 + (flat >> 3);
    const int bh = nid >> 4;
    const int q0 = (nid & 15) << 7;

    // Q fragments (B-operand: col=lane&15 -> q-row wv*16+lr, k-slice hi*8..+8)
    ushort8 qf[16];
    {
        const char* Qg = (const char*)(Q + ((size_t)bh * 2048 + q0 + wv * 16 + lr) * 512) + hi * 16;
#pragma unroll
        for (int ks = 0; ks < 16; ++ks) qf[ks] = *(const ushort8*)(Qg + ks * 64);
    }

    f32x4 acc[4][8] = {};   // [q 16-block within 64-row half][d 16-frag within 128-wide slice]
    float mrun = -1e30f, lrun = 0.f;   // per-lane, q = wv*16+lr (replicated over hi), base-2

    const char* Kg = (const char*)(K + (size_t)bh * 2048 * 512);
    const char* Vg = (const char*)(Vt + (size_t)bh * 512 * 2048);

    // S-phase: 32 MFMAs into two chains (keys lr / lr+16), zero-started
    auto s_phase = [&](const char* Kb, f32x4& s0, f32x4& s1) {
        s0 = (f32x4){0.f, 0.f, 0.f, 0.f};
        s1 = (f32x4){0.f, 0.f, 0.f, 0.f};
#pragma unroll
        for (int ks = 0; ks < 16; ++ks) {
            int swz = (ks * 64 + hi * 16) ^ ((lr & 7) << 4);
            ushort8 kf0 = *(const ushort8*)(Kb + lr * 1024 + swz);
            ushort8 kf1 = *(const ushort8*)(Kb + (lr + 16) * 1024 + swz);
            s0 = mfma16(kf0, qf[ks], s0);
            s1 = mfma16(kf1, qf[ks], s1);
        }
    };

    // softmax on a finished S pair; writes P/alpha/flag into slot pcb
    auto softmax_store = [&](const f32x4& s0, const f32x4& s1, int pcb) {
        float mx = fmaxf(fmaxf(fmaxf(s0[0], s0[1]), fmaxf(s0[2], s0[3])),
                         fmaxf(fmaxf(s1[0], s1[1]), fmaxf(s1[2], s1[3])));
        mx = fmaxf(mx, __shfl_xor(mx, 16));
        mx = fmaxf(mx, __shfl_xor(mx, 32));
        float a = 1.0f;
        bool upd = false;
        if (mx > mrun + 11.5f) { a = exp2f(mrun - mx); mrun = mx; upd = true; }   // defer-max
        float p[8];
#pragma unroll
        for (int r = 0; r < 4; ++r) {
            p[r]     = exp2f(s0[r] - mrun);
            p[4 + r] = exp2f(s1[r] - mrun);
        }
        float ps = ((p[0] + p[1]) + (p[2] + p[3])) + ((p[4] + p[5]) + (p[6] + p[7]));
        ps += __shfl_xor(ps, 16);
        ps += __shfl_xor(ps, 32);
        lrun = lrun * a + ps;

        const int qr = wv * 16 + lr;
        char* Pb = (char*)&Plds[pcb][0] + qr * 80;
        uint2 w01, w23;
        w01.x = (unsigned)f2bf(p[0]) | ((unsigned)f2bf(p[1]) << 16);
        w01.y = (unsigned)f2bf(p[2]) | ((unsigned)f2bf(p[3]) << 16);
        w23.x = (unsigned)f2bf(p[4]) | ((unsigned)f2bf(p[5]) << 16);
        w23.y = (unsigned)f2bf(p[6]) | ((unsigned)f2bf(p[7]) << 16);
        *(uint2*)(Pb + hi * 8) = w01;
        *(uint2*)(Pb + 32 + hi * 8) = w23;
        if (hi == 0) red[pcb][qr] = a;
        if (lane == 0) rflag[pcb][wv] = __any(upd) ? 1 : 0;
    };

    // rescale (defer-max gated) + PV for tile whose P sits in slot pcb, V tile at key ktv
    auto pv_phase = [&](int pcb, int ktv) {
        int anyupd = rflag[pcb][0] | rflag[pcb][1] | rflag[pcb][2] | rflag[pcb][3]
                   | rflag[pcb][4] | rflag[pcb][5] | rflag[pcb][6] | rflag[pcb][7];
        if (anyupd) {
#pragma unroll
            for (int mf = 0; mf < 4; ++mf) {
                f32x4 a4 = *(const f32x4*)&red[pcb][qh * 64 + mf * 16 + hi * 4];
#pragma unroll
                for (int nf = 0; nf < 8; ++nf)
#pragma unroll
                    for (int r = 0; r < 4; ++r) acc[mf][nf][r] *= a4[r];
            }
        }
        ushort8 pf[4];
#pragma unroll
        for (int mf = 0; mf < 4; ++mf)
            pf[mf] = *(const ushort8*)((const char*)&Plds[pcb][0]
                                       + (qh * 64 + mf * 16 + lr) * 80 + hi * 16);
        __builtin_amdgcn_s_setprio(1);
#pragma unroll
        for (int nf = 0; nf < 8; ++nf) {
            int d = ds * 128 + nf * 16 + lr;
            ushort8 vf = *(const ushort8*)(Vg + (size_t)d * 4096 + (size_t)ktv * 2 + hi * 16);
#pragma unroll
            for (int mf = 0; mf < 4; ++mf) acc[mf][nf] = mfma16(pf[mf], vf, acc[mf][nf]);
        }
        __builtin_amdgcn_s_setprio(0);
    };

    auto prefetch_k = [&](int tt) {   // stage K(tt) into buf tt&1
        const char* Kgt = Kg + (size_t)tt * 32 * 1024;
#pragma unroll
        for (int r4 = 0; r4 < 4; ++r4) {
            int r = wv * 4 + r4;
            gload_lds16(Kgt + (size_t)r * 1024 + ((lane ^ (r & 7)) << 4),
                        &Klds[tt & 1][(size_t)r * 512]);
        }
    };

    f32x4 s0c, s1c, s0p, s1p;

    // prologue: K(0) -> buf0
    prefetch_k(0);
    __syncthreads();                       // K0 ready

    // peeled iter 0: prefetch K(1), S(0); no softmax/PV yet
    prefetch_k(1);
    s_phase((const char*)&Klds[0][0], s0c, s1c);
    __syncthreads();                       // K1 DMA drained; S(0) reads of buf0 done

    for (int t = 1; t < 64; ++t) {
        if (t + 1 < 64) prefetch_k(t + 1);       // -> buf (t+1)&1 (= buf read by S(t-1), done)

        s0p = s0c; s1p = s1c;                     // retire S(t-1) results
        s_phase((const char*)&Klds[t & 1][0], s0c, s1c);   // S(t) in flight...
        softmax_store(s0p, s1p, (t - 1) & 1);     // ...while softmax(t-1) runs on VALU

        __syncthreads();   // P(t-1)/alpha visible; K(t+1) drained; buf[t&1] reads done

        pv_phase((t - 1) & 1, (t - 1) << 5);
    }

    // epilogue: tile 63
    softmax_store(s0c, s1c, 1);
    __syncthreads();
    pv_phase(1, 63 << 5);

    // final l for all 128 rows -> LDS
    if (hi == 0) lred[wv * 16 + lr] = lrun;
    __syncthreads();

    const int b = bh >> 3, h = bh & 7;
#pragma unroll
    for (int mf = 0; mf < 4; ++mf) {
        f32x4 lv = *(const f32x4*)&lred[qh * 64 + mf * 16 + hi * 4];
        f32x4 inv;
#pragma unroll
        for (int r = 0; r < 4; ++r) inv[r] = 1.0f / lv[r];
#pragma unroll
        for (int nf = 0; nf < 8; ++nf) {
            int d = ds * 128 + nf * 16 + lr;
#pragma unroll
            for (int r = 0; r < 4; ++r) {
                int t = q0 + qh * 64 + mf * 16 + hi * 4 + r;
                O[((size_t)(b * 2048 + t)) * 4096 + h * 512 + d] = f2bf(acc[mf][nf][r] * inv[r]);
            }
        }
    }
}

// ---------- host ----------
extern "C" void kernel_launch(void* const* d_in, const int* in_sizes, int n_in,
                              void* d_out, int out_size, void* d_ws, size_t ws_size,
                              hipStream_t stream) {
    const float* x  = (const float*)d_in[0];
    const float* Wq = (const float*)d_in[1];
    const float* Wk = (const float*)d_in[2];
    const float* Wv = (const float*)d_in[3];
    const float* Wu = (const float*)d_in[4];
    const float* bu = (const float*)d_in[5];

    char* ws = (char*)d_ws;
    const size_t MB = 1ull << 20;
    u16* xb  = (u16*)(ws + 0);          // 4 MB  x as bf16 [4096][512]
    u16* Wqt = (u16*)(ws + 4 * MB);     // 3 x 4 MB: Wq^T,Wk^T,Wv^T bf16 [4096][512] contiguous
    u16* Wut = (u16*)(ws + 16 * MB);    // 4 MB  Wu^T bf16 [512][4096]
    u16* Qb  = (u16*)(ws + 20 * MB);    // 2 x 32 MB: Q,K [bh][t][d] (Q pre-scaled); V slot unused
    u16* Kb  = (u16*)(ws + 52 * MB);
    u16* Vtb = (u16*)(ws + 116 * MB);   // 32 MB [bh][d][t] (written directly by gemm_qkv z=2)
    u16* Ob  = (u16*)(ws + 84 * MB);    // 32 MB [b*t][h*d]

    prep_kernel<<<4096, 256, 0, stream>>>(x, Wq, Wk, Wv, Wu, xb, Wqt, Wut);

    // 512^-0.5 * log2(e): softmax runs in base-2 (exp2f), fold conversion into Q scale
    const float s2 = 0.06375871593f;
    gemm_qkv<<<dim3(32, 32, 3), 256, 0, stream>>>(xb, Wqt, s2, Qb, Vtb);

    attn_kernel<<<256, 512, 0, stream>>>(Qb, Kb, Vtb, Ob);

    gemm_final<<<dim3(8, 32), 256, 0, stream>>>(Ob, Wut, bu, (float*)d_out, 4096);
}